// Round 2
// baseline (16412.215 us; speedup 1.0000x reference)
//
#include <hip/hip_runtime.h>
#include <cstdint>
#include <cstddef>

// ---------------- problem dims ----------------
#define SS   256
#define BB   32
#define EE   768
#define HH   1024
#define QQ   64
#define TTOP 512
#define NPC  16
#define G4   4096          // 4*H
#define KTOT 1792          // E + H (fused [x_t ; h] GEMM)
#define KSPLIT 16
#define KSL  112           // KTOT / KSPLIT
#define EPSF 1e-5f

// ---------------- ws layout (floats) ----------------
#define OFF_XNT   ((size_t)0)                       // [256][768][32]
#define OFF_WT    ((size_t)6291456)                 // [2][1792][4096]
#define OFF_HT    ((size_t)20971520)                // [2][1024][32]
#define OFF_CT    ((size_t)21037056)                // [2][1024][32]
#define OFF_PART  ((size_t)21102592)                // [16][8192][32] ; reused as f64 arena for eig
#define OFF_HS    ((size_t)25296896)                // [2][256][32][1024]
#define OFF_XQ    ((size_t)42074112)                // [2][256][32][64]
#define OFF_CMAT  ((size_t)43122688)                // [64][256][64]
#define OFF_COS   ((size_t)44171264)                // [64][256]
#define OFF_COV   ((size_t)44187648)                // [64][64][64] f32 cov
#define OFF_PG    ((size_t)44449792)                // [64][64][16] f32 top-evecs
// total 44515328 floats = ~178.1 MB

// LAPACK f32 machine constants (used for branch thresholds; math in f64)
#define EPS32D    5.9604644775390625e-8
#define EPS232D   (EPS32D*EPS32D)
#define SAFMIN32D 1.1754943508222875e-38

__device__ __forceinline__ float sigm(float x){ return 1.0f/(1.0f + expf(-x)); }

__device__ __forceinline__ double wsumd(double v){
  #pragma unroll
  for (int o = 32; o; o >>= 1) v += __shfl_xor(v, o, 64);
  return v;
}
__device__ __forceinline__ double wmaxd(double v){
  #pragma unroll
  for (int o = 32; o; o >>= 1) v = fmax(v, __shfl_xor(v, o, 64));
  return v;
}
// LAPACK >=3.10 dlartg convention: c = |f|/r >= 0, r = sign(f)*hypot
__device__ __forceinline__ void dlartg_(double f, double g, double& c, double& s, double& r){
  if (g == 0.0){ c = 1.0; s = 0.0; r = f; }
  else if (f == 0.0){ c = 0.0; s = (g >= 0.0) ? 1.0 : -1.0; r = fabs(g); }
  else {
    double d = sqrt(f*f + g*g);
    c = fabs(f)/d;
    r = copysign(d, f);
    s = g/r;
  }
}
// netlib dlaev2
__device__ void dlaev2_(double a, double b, double c,
                        double& rt1, double& rt2, double& cs1, double& sn1){
  double sm = a + c, df = a - c, adf = fabs(df), tb = b + b, ab = fabs(tb);
  double acmx, acmn;
  if (fabs(a) > fabs(c)){ acmx = a; acmn = c; } else { acmx = c; acmn = a; }
  double rt;
  if (adf > ab)      rt = adf*sqrt(1.0 + (ab/adf)*(ab/adf));
  else if (adf < ab) rt = ab*sqrt(1.0 + (adf/ab)*(adf/ab));
  else               rt = ab*sqrt(2.0);
  int sgn1;
  if (sm < 0.0){ rt1 = 0.5*(sm - rt); sgn1 = -1; rt2 = (acmx/rt1)*acmn - (b/rt1)*b; }
  else if (sm > 0.0){ rt1 = 0.5*(sm + rt); sgn1 = 1; rt2 = (acmx/rt1)*acmn - (b/rt1)*b; }
  else { rt1 = 0.5*rt; rt2 = -0.5*rt; sgn1 = 1; }
  double cs; int sgn2;
  if (df >= 0.0){ cs = df + rt; sgn2 = 1; } else { cs = df - rt; sgn2 = -1; }
  double acs = fabs(cs);
  if (acs > ab){ double ct = -tb/cs; sn1 = 1.0/sqrt(1.0+ct*ct); cs1 = ct*sn1; }
  else {
    if (ab == 0.0){ cs1 = 1.0; sn1 = 0.0; }
    else { double tn = -cs/tb; cs1 = 1.0/sqrt(1.0+tn*tn); sn1 = tn*cs1; }
  }
  if (sgn1 == sgn2){ double tn = cs1; cs1 = -sn1; sn1 = tn; }
}

// netlib dsteqr on a 16x16 leaf (COMPZ='I'); all 64 lanes run scalar flow
// redundantly; lanes 0..15 carry Z rows. z16 is [16][17] shared.
__device__ void dsteqr16_(int base, double* d, double* e, double* z16, int ln){
  if (ln < 16){
    #pragma unroll
    for (int j = 0; j < 16; j++) z16[ln*17+j] = (ln==j) ? 1.0 : 0.0;
  }
  __syncthreads();
  const int n = 16, nm1 = 15;
  int jtot = 0; const int nmaxit = 480;
  int l1 = 0;
  while (l1 < n){
    if (l1 > 0) e[base+l1-1] = 0.0;
    int m = nm1;
    for (int mm = l1; mm < nm1; mm++){
      double tst = fabs(e[base+mm]);
      if (tst == 0.0){ m = mm; break; }
      if (tst <= (sqrt(fabs(d[base+mm]))*sqrt(fabs(d[base+mm+1])))*EPS32D){
        e[base+mm] = 0.0; m = mm; break;
      }
    }
    int l = l1, lend = m;
    l1 = m + 1;
    if (lend == l) continue;
    if (fabs(d[base+lend]) < fabs(d[base+l])){ int t = l; l = lend; lend = t; }
    if (lend > l){
      // ---- QL ----
      for (;;){
        int mm = lend;
        for (int k2 = l; k2 < lend; k2++){
          double tst = e[base+k2]*e[base+k2];
          if (tst <= (EPS232D*fabs(d[base+k2]))*fabs(d[base+k2+1]) + SAFMIN32D){ mm = k2; break; }
        }
        if (mm < lend) e[base+mm] = 0.0;
        double p = d[base+l];
        if (mm == l){ l++; if (l <= lend) continue; break; }
        if (mm == l+1){
          double rt1, rt2, cc, ss;
          dlaev2_(d[base+l], e[base+l], d[base+l+1], rt1, rt2, cc, ss);
          if (ln < 16){
            double x = z16[ln*17+l], y = z16[ln*17+l+1];
            z16[ln*17+l]   = cc*x + ss*y;
            z16[ln*17+l+1] = cc*y - ss*x;
          }
          d[base+l] = rt1; d[base+l+1] = rt2; e[base+l] = 0.0;
          l += 2; if (l <= lend) continue; break;
        }
        if (jtot == nmaxit) break;
        jtot++;
        double g = (d[base+l+1]-p)/(2.0*e[base+l]);
        double r = sqrt(g*g+1.0);
        g = d[base+mm] - p + e[base+l]/(g + copysign(r, g));
        double s2 = 1.0, c2 = 1.0; p = 0.0;
        for (int i = mm-1; i >= l; i--){
          double f = s2*e[base+i], b = c2*e[base+i];
          dlartg_(g, f, c2, s2, r);
          if (i != mm-1) e[base+i+1] = r;
          g = d[base+i+1] - p;
          r = (d[base+i]-g)*s2 + 2.0*c2*b;
          p = s2*r;
          d[base+i+1] = g + p;
          g = c2*r - b;
          // saved rotation is (c, -s) applied backward == immediate apply
          if (ln < 16){
            double x = z16[ln*17+i], y = z16[ln*17+i+1];
            z16[ln*17+i]   = c2*x - s2*y;
            z16[ln*17+i+1] = s2*x + c2*y;
          }
        }
        d[base+l] -= p; e[base+l] = g;
      }
    } else {
      // ---- QR ----
      for (;;){
        int mm = lend;
        for (int k2 = l; k2 > lend; k2--){
          double tst = e[base+k2-1]*e[base+k2-1];
          if (tst <= (EPS232D*fabs(d[base+k2]))*fabs(d[base+k2-1]) + SAFMIN32D){ mm = k2; break; }
        }
        if (mm > lend) e[base+mm-1] = 0.0;
        double p = d[base+l];
        if (mm == l){ l--; if (l >= lend) continue; break; }
        if (mm == l-1){
          double rt1, rt2, cc, ss;
          dlaev2_(d[base+l-1], e[base+l-1], d[base+l], rt1, rt2, cc, ss);
          if (ln < 16){
            double x = z16[ln*17+l-1], y = z16[ln*17+l];
            z16[ln*17+l-1] = cc*x + ss*y;
            z16[ln*17+l]   = cc*y - ss*x;
          }
          d[base+l-1] = rt1; d[base+l] = rt2; e[base+l-1] = 0.0;
          l -= 2; if (l >= lend) continue; break;
        }
        if (jtot == nmaxit) break;
        jtot++;
        double g = (d[base+l-1]-p)/(2.0*e[base+l-1]);
        double r = sqrt(g*g+1.0);
        g = d[base+mm] - p + e[base+l-1]/(g + copysign(r, g));
        double s2 = 1.0, c2 = 1.0; p = 0.0;
        for (int i = mm; i <= l-1; i++){
          double f = s2*e[base+i], b = c2*e[base+i];
          dlartg_(g, f, c2, s2, r);
          if (i != mm) e[base+i-1] = r;
          g = d[base+i] - p;
          r = (d[base+i+1]-g)*s2 + 2.0*c2*b;
          p = s2*r;
          d[base+i] = g + p;
          g = c2*r - b;
          if (ln < 16){
            double x = z16[ln*17+i], y = z16[ln*17+i+1];
            z16[ln*17+i]   = c2*x + s2*y;
            z16[ln*17+i+1] = c2*y - s2*x;
          }
        }
        d[base+l] -= p; e[base+l-1] = g;
      }
    }
  }
  // selection sort ascending (column swaps only)
  for (int ii = 1; ii < n; ii++){
    int i = ii-1, k = i; double p = d[base+i];
    for (int j = ii; j < n; j++) if (d[base+j] < p){ k = j; p = d[base+j]; }
    if (k != i){
      d[base+k] = d[base+i]; d[base+i] = p;
      if (ln < 16){ double t = z16[ln*17+i]; z16[ln*17+i] = z16[ln*17+k]; z16[ln*17+k] = t; }
    }
  }
  __syncthreads();
}

// dlaed1/2/3-style rank-one merge on block [base, base+n1+n2)
__device__ void dc_merge(int base, int n1, int n2, double rho_in, int ln,
    double* s_d, double* Zt, double* Tt,
    double* md, double* mz, double* dl, double* wz, double* lam, double* zh,
    double* ev, double* su, int* indx, int* sec, int* defl, int* prm){
  int n = n1 + n2;
  double zv = 0.0;
  if (ln < n){
    if (ln < n1) zv = Zt[(size_t)(base+n1-1)*64 + base + ln];
    else         zv = Zt[(size_t)(base+n1)*64 + base + ln];
    if (rho_in < 0.0 && ln >= n1) zv = -zv;
  }
  zv *= 0.70710678118654752440;
  mz[ln] = (ln < n) ? zv : 0.0;
  md[ln] = (ln < n) ? s_d[base+ln] : 0.0;
  __syncthreads();
  double rho = fabs(2.0*rho_in);
  if (ln == 0){
    int i1 = 0, i2 = n1, k = 0;
    while (i1 < n1 && i2 < n){
      if (md[i2] < md[i1]) indx[k++] = i2++; else indx[k++] = i1++;
    }
    while (i1 < n1) indx[k++] = i1++;
    while (i2 < n)  indx[k++] = i2++;
  }
  __syncthreads();
  double dmax = wmaxd((ln<n) ? fabs(md[ln]) : 0.0);
  double zmax = wmaxd((ln<n) ? fabs(mz[ln]) : 0.0);
  double tol = 8.0*EPS32D*fmax(dmax, zmax);
  int K = 0, ndefl = 0, pj = -1;
  for (int j = 0; j < n; j++){
    int nj = indx[j];
    if (rho*fabs(mz[nj]) <= tol){
      defl[ndefl++] = nj;                      // type-1 deflation
    } else if (pj < 0){
      pj = nj;
    } else {
      double sG = mz[pj], cG = mz[nj];
      double tau = sqrt(cG*cG + sG*sG);
      double tdf = md[nj] - md[pj];
      double c = cG/tau, s = -sG/tau;
      if (fabs(tdf*c*s) <= tol){
        // type-2 deflation: Givens on columns pj, nj
        mz[nj] = tau; mz[pj] = 0.0;
        if (ln < n){
          double x = Zt[(size_t)(base+ln)*64 + base+pj];
          double y = Zt[(size_t)(base+ln)*64 + base+nj];
          Zt[(size_t)(base+ln)*64 + base+pj] = c*x + s*y;
          Zt[(size_t)(base+ln)*64 + base+nj] = c*y - s*x;
        }
        __syncthreads();
        double t2 = md[pj]*c*c + md[nj]*s*s;
        double t3 = md[pj]*s*s + md[nj]*c*c;
        md[nj] = t3; md[pj] = t2;
        defl[ndefl++] = pj;
        pj = nj;
      } else {
        sec[K] = pj; dl[K] = md[pj]; wz[K] = mz[pj]; K++;
        pj = nj;
      }
    }
  }
  if (pj >= 0){ sec[K] = pj; dl[K] = md[pj]; wz[K] = mz[pj]; K++; }
  __syncthreads();
  double wsum2 = wsumd((ln < K) ? wz[ln]*wz[ln] : 0.0);
  if (ln < K){
    double lo = dl[ln];
    double hi = (ln < K-1) ? dl[ln+1] : (dl[K-1] + rho*wsum2);
    for (int it = 0; it < 120; it++){
      double mid = 0.5*(lo+hi);
      if (!(mid > lo) || !(mid < hi)) break;
      double fv = 1.0;
      for (int i2 = 0; i2 < K; i2++) fv += rho*wz[i2]*wz[i2]/(dl[i2]-mid);
      if (fv < 0.0) lo = mid; else hi = mid;
    }
    double lj = 0.5*(lo+hi);
    if (!(lj > dl[ln])) lj = nextafter(dl[ln], 1.0e300);
    lam[ln] = lj;
  }
  __syncthreads();
  if (ln < K){
    double di = dl[ln];
    double prod = lam[K-1] - di;
    for (int j2 = 0; j2 < ln; j2++)   prod *= (lam[j2]-di)/(dl[j2]-di);
    for (int j2 = ln; j2 < K-1; j2++) prod *= (lam[j2]-di)/(dl[j2+1]-di);
    zh[ln] = copysign(sqrt(fabs(prod)), wz[ln]);   // Gu-Eisenstat
  }
  __syncthreads();
  for (int j = 0; j < K; j++){
    double ui = (ln < K) ? zh[ln]/(dl[ln]-lam[j]) : 0.0;
    double nrm = sqrt(wsumd(ui*ui));
    su[ln] = ui/nrm;
    __syncthreads();
    if (ln < n){
      double acc = 0.0;
      for (int i2 = 0; i2 < K; i2++)
        acc += Zt[(size_t)(base+ln)*64 + base + sec[i2]]*su[i2];
      Tt[(size_t)ln*64 + j] = acc;
    }
    if (ln == 0) ev[j] = lam[j];
    __syncthreads();
  }
  for (int j = 0; j < ndefl; j++){
    int cj = defl[j];
    if (ln < n) Tt[(size_t)ln*64 + K + j] = Zt[(size_t)(base+ln)*64 + base + cj];
    if (ln == 0) ev[K+j] = md[cj];
  }
  __syncthreads();
  if (ln == 0){
    for (int i2 = 0; i2 < n; i2++) prm[i2] = i2;
    for (int a2 = 0; a2 < n-1; a2++){
      int kk = a2;
      for (int b2 = a2+1; b2 < n; b2++) if (ev[prm[b2]] < ev[prm[kk]]) kk = b2;
      int t3 = prm[a2]; prm[a2] = prm[kk]; prm[kk] = t3;
    }
  }
  __syncthreads();
  if (ln < n){
    for (int c2 = 0; c2 < n; c2++)
      Zt[(size_t)(base+ln)*64 + base + c2] = Tt[(size_t)ln*64 + prm[c2]];
  }
  if (ln == 0){ for (int c2 = 0; c2 < n; c2++) s_d[base+c2] = ev[prm[c2]]; }
  __syncthreads();
}

// ---------------- ssyevd-faithful eigensolver, one 64x64 matrix per block ----
__global__ __launch_bounds__(64) void k_eig(const float* __restrict__ covg,
                                            double* __restrict__ dar,
                                            float* __restrict__ Pg){
  int u = blockIdx.x, ln = threadIdx.x;
  double* A  = dar + (size_t)u*16384;
  double* Qh = A + 4096;
  double* Zt = A + 8192;
  double* Tt = A + 12288;
  __shared__ double s_d[64], s_e[64], s_tau[64], s_v[64], s_w[64];
  __shared__ double md[64], mz[64], dl[64], wz[64], lam[64], zh[64], ev[64], su[64];
  __shared__ double z16[16*17];
  __shared__ int indx[64], sec[64], defl[64], prm[64];

  for (int n = ln; n < 4096; n += 64) A[n] = (double)covg[(size_t)u*4096 + n];
  __syncthreads();

  // ---- dsytd2 (lower) ----
  for (int i = 0; i < 63; i++){
    double alpha = A[(size_t)(i+1)*64 + i];
    double xv = (ln >= i+2) ? A[(size_t)ln*64 + i] : 0.0;
    double xnorm2 = wsumd(xv*xv);
    if (xnorm2 == 0.0){
      if (ln == 0){ s_e[i] = alpha; s_tau[i] = 0.0; }
    } else {
      double beta = -copysign(sqrt(alpha*alpha + xnorm2), alpha);
      double taui = (beta - alpha)/beta;
      double sc = 1.0/(alpha - beta);
      s_v[ln] = (ln == i+1) ? 1.0 : ((ln >= i+2) ? A[(size_t)ln*64+i]*sc : 0.0);
      __syncthreads();
      if (ln >= i+2) A[(size_t)ln*64+i] = s_v[ln];   // store v like LAPACK
      double wr = 0.0;
      if (ln >= i+1){
        for (int c2 = i+1; c2 < 64; c2++){
          double av = (ln >= c2) ? A[(size_t)ln*64+c2] : A[(size_t)c2*64+ln];
          wr += av*s_v[c2];
        }
        wr *= taui;
      }
      double dotwv = wsumd((ln >= i+1) ? wr*s_v[ln] : 0.0);
      double alp2 = -0.5*taui*dotwv;
      wr += alp2*s_v[ln];
      s_w[ln] = (ln >= i+1) ? wr : 0.0;
      __syncthreads();
      if (ln >= i+1){
        for (int c2 = i+1; c2 <= ln; c2++)
          A[(size_t)ln*64+c2] -= s_v[ln]*s_w[c2] + s_w[ln]*s_v[c2];
      }
      if (ln == 0){ s_e[i] = beta; s_tau[i] = taui; }
    }
    __syncthreads();
  }
  s_d[ln] = A[(size_t)ln*64+ln];
  __syncthreads();

  // ---- form Q = H_0 H_1 ... (sorgtr-equivalent) ----
  for (int n = ln; n < 4096; n += 64) Qh[n] = 0.0;
  __syncthreads();
  Qh[(size_t)ln*64+ln] = 1.0;
  __syncthreads();
  for (int i = 62; i >= 0; i--){
    double taui = s_tau[i];
    if (taui != 0.0){
      s_v[ln] = (ln == i+1) ? 1.0 : ((ln >= i+2) ? A[(size_t)ln*64+i] : 0.0);
      __syncthreads();
      double dj = 0.0;
      for (int r2 = i+1; r2 < 64; r2++) dj += s_v[r2]*Qh[(size_t)r2*64+ln];
      dj *= taui;
      for (int r2 = i+1; r2 < 64; r2++) Qh[(size_t)r2*64+ln] -= s_v[r2]*dj;
    }
    __syncthreads();
  }

  // ---- dlaed0: corner adjust, 4x16 leaves, 3 merges ----
  double rho_a = s_e[15], rho_b = s_e[47], rho_top = s_e[31];
  if (ln == 0){
    s_d[15] -= fabs(rho_a);   s_d[16] -= fabs(rho_a);
    s_d[31] -= fabs(rho_top); s_d[32] -= fabs(rho_top);
    s_d[47] -= fabs(rho_b);   s_d[48] -= fabs(rho_b);
  }
  for (int n = ln; n < 4096; n += 64) Zt[n] = 0.0;
  __syncthreads();
  for (int leaf = 0; leaf < 4; leaf++){
    dsteqr16_(leaf*16, s_d, s_e, z16, ln);
    if (ln < 16){
      for (int j = 0; j < 16; j++)
        Zt[(size_t)(leaf*16+ln)*64 + leaf*16 + j] = z16[ln*17+j];
    }
    __syncthreads();
  }
  dc_merge(0, 16, 16, rho_a, ln, s_d, Zt, Tt, md, mz, dl, wz, lam, zh, ev, su, indx, sec, defl, prm);
  dc_merge(32, 16, 16, rho_b, ln, s_d, Zt, Tt, md, mz, dl, wz, lam, zh, ev, su, indx, sec, defl, prm);
  dc_merge(0, 32, 32, rho_top, ln, s_d, Zt, Tt, md, mz, dl, wz, lam, zh, ev, su, indx, sec, defl, prm);

  // ---- U = Q * Z ; emit top-16 descending (cols 63..48) ----
  for (int nn = 0; nn < 16; nn++){
    double acc = 0.0;
    for (int k = 0; k < 64; k++)
      acc += Qh[(size_t)ln*64+k]*Zt[(size_t)k*64 + (63-nn)];
    Pg[(size_t)u*1024 + ln*16 + nn] = (float)acc;
  }
}

// ---------------- input layer norm -> xnT[t][e][b] ----------------
__global__ void k_ln_in(const float* __restrict__ x, const float* __restrict__ g,
                        const float* __restrict__ be, float* __restrict__ xnT){
  int bid = blockIdx.x; int s = bid >> 5, b = bid & 31;
  int tid = threadIdx.x;
  const float* row = x + ((size_t)(s*BB + b))*EE;
  __shared__ float r1[256], r2[256];
  float su = 0.f, sq = 0.f;
  for (int e = tid; e < EE; e += 256){ float v = row[e]; su += v; sq += v*v; }
  r1[tid] = su; r2[tid] = sq; __syncthreads();
  for (int st = 128; st > 0; st >>= 1){
    if (tid < st){ r1[tid] += r1[tid+st]; r2[tid] += r2[tid+st]; }
    __syncthreads();
  }
  float mu  = r1[0] * (1.0f/EE);
  float var = r2[0] * (1.0f/EE) - mu*mu;
  float rstd = rsqrtf(var + EPSF);
  for (int e = tid; e < EE; e += 256){
    float v = (row[e]-mu)*rstd*g[e] + be[e];
    xnT[((size_t)s*EE + e)*BB + b] = v;
  }
}

// ---------------- build WT[d][k][r] = concat(Wih;Whh)^T ----------------
__global__ void k_transW(const float* __restrict__ Wih_f, const float* __restrict__ Whh_f,
                         const float* __restrict__ Wih_b, const float* __restrict__ Whh_b,
                         float* __restrict__ WT){
  int d  = blockIdx.z;
  const float* Wih = d ? Wih_b : Wih_f;
  const float* Whh = d ? Whh_b : Whh_f;
  int rt = blockIdx.x*32, kt = blockIdx.y*32;
  int tx = threadIdx.x & 31, ty = threadIdx.x >> 5;   // 32 x 8
  __shared__ float tile[32][33];
  for (int i = ty; i < 32; i += 8){
    int r = rt + i, k = kt + tx;
    float v = (k < EE) ? Wih[(size_t)r*EE + k] : Whh[(size_t)r*HH + (k-EE)];
    tile[i][tx] = v;
  }
  __syncthreads();
  for (int i = ty; i < 32; i += 8){
    int k = kt + i, r = rt + tx;
    WT[((size_t)d*KTOT + k)*G4 + r] = tile[tx][i];
  }
}

__global__ void k_zero(float* __restrict__ p, int n){
  int i = blockIdx.x*blockDim.x + threadIdx.x;
  if (i < n) p[i] = 0.f;
}

// ---------------- per-step gates GEMM (K-split into partials) ----------------
__global__ __launch_bounds__(256) void k_step(const float* __restrict__ xnT,
        const float* __restrict__ WT, const float* __restrict__ hT,
        float* __restrict__ part, int t){
  int bid = blockIdx.x;
  int rc = bid >> 4, ks = bid & 15;
  int d  = rc >> 3;
  int tid = threadIdx.x;
  int rg = tid & 63, bg = tid >> 6;
  int b0 = bg*8;
  int rloc = (rc & 7)*512 + rg*8;          // row within dir [0,4096)
  int tt = d ? (SS-1-t) : t;
  const float* xn_t = xnT + (size_t)tt*EE*BB;
  const float* hT_d = hT  + (size_t)d*HH*BB;
  const float* WT_d = WT  + (size_t)d*KTOT*G4;
  __shared__ float Al[16*32];
  float acc[8][8];
  #pragma unroll
  for (int i = 0; i < 8; i++)
    #pragma unroll
    for (int j = 0; j < 8; j++) acc[i][j] = 0.f;
  int kbase = ks*KSL;
  for (int kc = 0; kc < KSL; kc += 16){
    #pragma unroll
    for (int u = 0; u < 2; u++){
      int n = tid*2 + u; int kl = n >> 5, bb = n & 31; int kk = kbase + kc + kl;
      Al[n] = (kk < EE) ? xn_t[(size_t)kk*BB + bb] : hT_d[(size_t)(kk-EE)*BB + bb];
    }
    __syncthreads();
    #pragma unroll
    for (int kl = 0; kl < 16; kl++){
      int kk = kbase + kc + kl;
      const float* wp = WT_d + (size_t)kk*G4 + rloc;
      float4 w0 = *(const float4*)(wp);
      float4 w1 = *(const float4*)(wp+4);
      float4 a0 = *(const float4*)(&Al[kl*32 + b0]);
      float4 a1 = *(const float4*)(&Al[kl*32 + b0 + 4]);
      float av[8] = {a0.x,a0.y,a0.z,a0.w,a1.x,a1.y,a1.z,a1.w};
      float wv[8] = {w0.x,w0.y,w0.z,w0.w,w1.x,w1.y,w1.z,w1.w};
      #pragma unroll
      for (int bi = 0; bi < 8; bi++)
        #pragma unroll
        for (int ri = 0; ri < 8; ri++) acc[bi][ri] += av[bi]*wv[ri];
    }
    __syncthreads();
  }
  int rglob = d*4096 + rloc;
  #pragma unroll
  for (int ri = 0; ri < 8; ri++){
    float4 o0 = make_float4(acc[0][ri],acc[1][ri],acc[2][ri],acc[3][ri]);
    float4 o1 = make_float4(acc[4][ri],acc[5][ri],acc[6][ri],acc[7][ri]);
    float* op = part + ((size_t)ks*8192 + rglob + ri)*BB + b0;
    *(float4*)op = o0; *(float4*)(op+4) = o1;
  }
}

// ---------------- per-step pointwise LSTM update ----------------
__global__ void k_upd(const float* __restrict__ part,
                      const float* __restrict__ bih_f, const float* __restrict__ bhh_f,
                      const float* __restrict__ bih_b, const float* __restrict__ bhh_b,
                      float* __restrict__ hT, float* __restrict__ cT,
                      float* __restrict__ hs, int t){
  int bid = blockIdx.x; int d = bid >> 7, jc = bid & 127;
  int tid = threadIdx.x; int b = tid & 31, jj = tid >> 5;
  int j = jc*8 + jj;
  const float* bih = d ? bih_b : bih_f;
  const float* bhh = d ? bhh_b : bhh_f;
  float gv[4];
  #pragma unroll
  for (int g = 0; g < 4; g++){
    int r = d*G4 + g*HH + j;
    float s = bih[g*HH+j] + bhh[g*HH+j];
    #pragma unroll
    for (int ks = 0; ks < KSPLIT; ks++) s += part[((size_t)ks*8192 + r)*BB + b];
    gv[g] = s;
  }
  float iv = sigm(gv[0]), fv = sigm(gv[1]), gg = tanhf(gv[2]), ov = sigm(gv[3]);
  size_t sidx = ((size_t)d*HH + j)*BB + b;
  float c = cT[sidx];
  c = fv*c + iv*gg;
  cT[sidx] = c;
  float h = ov*tanhf(c);
  hT[sidx] = h;
  int tsv = d ? (SS-1-t) : t;
  hs[(((size_t)d*SS + tsv)*BB + b)*HH + j] = h;
}

// ---------------- LN(hs) + tanh(Wsq proj) -> xq[d][t][b][q] ----------------
__global__ __launch_bounds__(256) void k_lnproj(const float* __restrict__ hs,
        const float* __restrict__ g_fw, const float* __restrict__ be_fw,
        const float* __restrict__ g_bk, const float* __restrict__ be_bk,
        const float* __restrict__ Wsq, const float* __restrict__ bsq,
        float* __restrict__ xq){
  int t = blockIdx.x, d = blockIdx.y;
  int tid = threadIdx.x;
  const float* gv  = d ? g_bk  : g_fw;
  const float* bev = d ? be_bk : be_fw;
  const float* hrow = hs + ((size_t)d*SS + t)*BB*HH;
  __shared__ float red[256], red2[256];
  __shared__ float smu[32], srs[32];
  __shared__ float ln[32*132];
  __shared__ float wl[64*132];
  {
    int b = tid >> 3, sl = tid & 7;
    const float* hp = hrow + (size_t)b*HH + sl*128;
    float s = 0.f, s2 = 0.f;
    for (int i = 0; i < 128; i += 4){
      float4 v = *(const float4*)(hp+i);
      s  += v.x+v.y+v.z+v.w;
      s2 += v.x*v.x+v.y*v.y+v.z*v.z+v.w*v.w;
    }
    red[tid] = s; red2[tid] = s2; __syncthreads();
    if (tid < 32){
      float a = 0.f, a2 = 0.f;
      for (int k = 0; k < 8; k++){ a += red[tid*8+k]; a2 += red2[tid*8+k]; }
      float mu = a*(1.f/HH), var = a2*(1.f/HH) - mu*mu;
      smu[tid] = mu; srs[tid] = rsqrtf(var + EPSF);
    }
    __syncthreads();
  }
  float acc[4][2] = {{0.f,0.f},{0.f,0.f},{0.f,0.f},{0.f,0.f}};
  int qg = tid & 31, bg = tid >> 5;
  int q0 = qg*2, b0g = bg*4;
  for (int jc = 0; jc < 8; jc++){
    for (int n = tid; n < 4096; n += 256){
      int b = n >> 7, jj = n & 127; int j = jc*128 + jj;
      float v = hrow[(size_t)b*HH + j];
      ln[b*132+jj] = (v - smu[b])*srs[b]*gv[j] + bev[j];
    }
    for (int n = tid; n < 8192; n += 256){
      int q = n >> 7, jj = n & 127;
      wl[q*132+jj] = Wsq[(size_t)q*HH + jc*128 + jj];
    }
    __syncthreads();
    for (int jj = 0; jj < 128; jj += 4){
      float4 w0 = *(const float4*)(&wl[q0*132+jj]);
      float4 w1 = *(const float4*)(&wl[(q0+1)*132+jj]);
      #pragma unroll
      for (int i = 0; i < 4; i++){
        float4 xv = *(const float4*)(&ln[(b0g+i)*132+jj]);
        acc[i][0] += xv.x*w0.x + xv.y*w0.y + xv.z*w0.z + xv.w*w0.w;
        acc[i][1] += xv.x*w1.x + xv.y*w1.y + xv.z*w1.z + xv.w*w1.w;
      }
    }
    __syncthreads();
  }
  #pragma unroll
  for (int i = 0; i < 4; i++)
    #pragma unroll
    for (int u = 0; u < 2; u++){
      float o = tanhf(acc[i][u] + bsq[q0+u]);
      xq[(((size_t)d*SS + t)*BB + (b0g+i))*QQ + q0 + u] = o;
    }
}

// ---------------- concat + LN + topic GEMM -> d_out topic_preds ----------------
__global__ __launch_bounds__(256) void k_topic(const float* __restrict__ xq,
        const float* __restrict__ g_sq, const float* __restrict__ be_sq,
        const float* __restrict__ Wtop, const float* __restrict__ btop,
        float* __restrict__ out){
  int t = blockIdx.x; int tid = threadIdx.x;
  __shared__ float xc[32*132];
  __shared__ float wl[16*520];
  __shared__ float red[256], red2[256];
  __shared__ float smu[32], srs[32];
  for (int n = tid; n < 4096; n += 256){
    int b = n >> 7, q = n & 127;
    float v = (q < 64) ? xq[(((size_t)0*SS + t)*BB + b)*QQ + q]
                       : xq[(((size_t)1*SS + t)*BB + b)*QQ + (q-64)];
    xc[b*132+q] = v;
  }
  __syncthreads();
  {
    int b = tid >> 3, sl = tid & 7;
    float s = 0.f, s2 = 0.f;
    for (int k = 0; k < 16; k++){ float v = xc[b*132 + sl*16 + k]; s += v; s2 += v*v; }
    red[tid] = s; red2[tid] = s2; __syncthreads();
    if (tid < 32){
      float a = 0.f, a2 = 0.f;
      for (int k = 0; k < 8; k++){ a += red[tid*8+k]; a2 += red2[tid*8+k]; }
      float mu = a*(1.f/128.f), var = a2*(1.f/128.f) - mu*mu;
      smu[tid] = mu; srs[tid] = rsqrtf(var + EPSF);
    }
    __syncthreads();
    for (int n = tid; n < 4096; n += 256){
      int b2 = n >> 7, q = n & 127;
      xc[b2*132+q] = (xc[b2*132+q]-smu[b2])*srs[b2]*g_sq[q] + be_sq[q];
    }
    __syncthreads();
  }
  int og = tid & 63, bg = tid >> 6;
  int o0 = og*8, b0 = bg*8;
  float acc[8][8];
  #pragma unroll
  for (int i = 0; i < 8; i++)
    #pragma unroll
    for (int j = 0; j < 8; j++) acc[i][j] = 0.f;
  for (int kc = 0; kc < 128; kc += 16){
    for (int n = tid; n < 8192; n += 256){
      int o = n >> 4, kk = n & 15;
      wl[kk*520 + o] = Wtop[(size_t)o*128 + kc + kk];
    }
    __syncthreads();
    #pragma unroll
    for (int kk = 0; kk < 16; kk++){
      float4 w0 = *(const float4*)(&wl[kk*520+o0]);
      float4 w1 = *(const float4*)(&wl[kk*520+o0+4]);
      float wv[8] = {w0.x,w0.y,w0.z,w0.w,w1.x,w1.y,w1.z,w1.w};
      int k = kc + kk;
      #pragma unroll
      for (int bi = 0; bi < 8; bi++){
        float xv = xc[(b0+bi)*132 + k];
        #pragma unroll
        for (int oi = 0; oi < 8; oi++) acc[bi][oi] += xv*wv[oi];
      }
    }
    __syncthreads();
  }
  #pragma unroll
  for (int bi = 0; bi < 8; bi++){
    int b = b0 + bi;
    #pragma unroll
    for (int oi = 0; oi < 8; oi++)
      out[((size_t)t*BB + b)*TTOP + o0 + oi] = acc[bi][oi] + btop[o0+oi];
  }
}

// ---------------- per-(dir,batch): mean, center, covariance ----------------
__global__ __launch_bounds__(256) void k_pca1(const float* __restrict__ xq,
        float* __restrict__ cmat, float* __restrict__ covg){
  int u = blockIdx.x; int d = u >> 5, b = u & 31;
  int tid = threadIdx.x;
  __shared__ float red[256];
  __shared__ float smq[64];
  {
    int q = tid & 63, tg = tid >> 6;
    float s = 0.f;
    for (int t2 = tg*64; t2 < tg*64+64; t2++)
      s += xq[(((size_t)d*SS + t2)*BB + b)*QQ + q];
    red[tid] = s; __syncthreads();
    if (tid < 64) smq[tid] = (red[tid]+red[tid+64]+red[tid+128]+red[tid+192])*(1.f/SS);
    __syncthreads();
  }
  float* cm = cmat + (size_t)u*SS*QQ;
  for (int n = tid; n < SS*QQ; n += 256){
    int t2 = n >> 6, q = n & 63;
    cm[n] = xq[(((size_t)d*SS + t2)*BB + b)*QQ + q] - smq[q];
  }
  __syncthreads();
  {
    int pg = (tid & 15)*4, qg = (tid >> 4)*4;
    float a[4][4] = {{0}};
    for (int t2 = 0; t2 < SS; t2++){
      const float* cr = cm + (size_t)t2*QQ;
      float4 cp = *(const float4*)(cr+pg);
      float4 cq = *(const float4*)(cr+qg);
      float pv[4] = {cp.x,cp.y,cp.z,cp.w}, qv[4] = {cq.x,cq.y,cq.z,cq.w};
      #pragma unroll
      for (int i = 0; i < 4; i++)
        #pragma unroll
        for (int j2 = 0; j2 < 4; j2++) a[i][j2] += pv[i]*qv[j2];
    }
    #pragma unroll
    for (int i = 0; i < 4; i++)
      #pragma unroll
      for (int j2 = 0; j2 < 4; j2++)
        covg[(size_t)u*4096 + (pg+i)*64 + qg+j2] = a[i][j2]*(1.f/SS);
  }
}

// ---------------- project + smooth + adjacent-cos ----------------
__global__ __launch_bounds__(256) void k_pca2(const float* __restrict__ cmat,
        const float* __restrict__ Pg, const float* __restrict__ kern,
        float* __restrict__ cosb){
  int u = blockIdx.x; int tid = threadIdx.x;
  __shared__ float sP[1024];
  __shared__ float sE[4096];
  __shared__ float sY[4096];
  __shared__ float kb[121];
  __shared__ float nn2[256];
  if (tid < 121) kb[tid] = kern[tid];
  for (int n = tid; n < 1024; n += 256) sP[n] = Pg[(size_t)u*1024 + n];
  __syncthreads();
  const float* cm = cmat + (size_t)u*SS*QQ;
  for (int m = tid; m < SS*NPC; m += 256){
    int t2 = m >> 4, n = m & 15;
    const float* cr = cm + (size_t)t2*QQ;
    float acc = 0.f;
    for (int i = 0; i < 64; i++) acc += cr[i]*sP[i*16+n];
    sE[m] = acc;
  }
  __syncthreads();
  for (int m = tid; m < SS*NPC; m += 256){
    int t2 = m >> 4, n = m & 15;
    float acc = 0.f;
    for (int a2 = 0; a2 < 11; a2++){
      int ta = t2 + a2 - 5;
      if (ta < 0 || ta >= SS) continue;
      #pragma unroll
      for (int b2 = 0; b2 < 11; b2++){
        int nb = n + b2 - 5;
        if (nb < 0 || nb >= NPC) continue;
        acc += kb[a2*11+b2]*sE[ta*16+nb];
      }
    }
    sY[m] = acc;
  }
  __syncthreads();
  {
    float acc = 0.f;
    #pragma unroll
    for (int n = 0; n < 16; n++){ float v = sY[tid*16+n]; acc += v*v; }
    nn2[tid] = acc;
  }
  __syncthreads();
  if (tid < 255){
    float num = 0.f;
    #pragma unroll
    for (int n = 0; n < 16; n++) num += sY[tid*16+n]*sY[(tid+1)*16+n];
    cosb[(size_t)u*256 + tid] = num/(sqrtf(nn2[tid])*sqrtf(nn2[tid+1]));
  }
}

// ---------------- d = sqrt(cf*cb); pos = argmax (np semantics: NaN wins) ----
__global__ void k_pos(const float* __restrict__ cosb, float* __restrict__ out){
  __shared__ float mx[256];
  __shared__ int   mi[256];
  int tid = threadIdx.x;
  for (int b = 0; b < 32; b++){
    float v = -1e30f;
    if (tid < 255){
      float cf = cosb[(size_t)(b)*256 + tid];
      float cb = cosb[(size_t)(32+b)*256 + tid];
      v = sqrtf(cf*cb);
      if (isnan(v)) v = INFINITY;   // np.argmax treats NaN as max, first occurrence
    }
    mx[tid] = v; __syncthreads();
    for (int st = 128; st > 0; st >>= 1){
      if (tid < st) mx[tid] = fmaxf(mx[tid], mx[tid+st]);
      __syncthreads();
    }
    float m = mx[0]; __syncthreads();
    mi[tid] = (tid < 255 && v == m) ? tid : (1<<30);
    __syncthreads();
    for (int st = 128; st > 0; st >>= 1){
      if (tid < st) mi[tid] = min(mi[tid], mi[tid+st]);
      __syncthreads();
    }
    if (tid == 0) out[(size_t)SS*BB*TTOP + b] = (float)mi[0];
    __syncthreads();
  }
}

// ---------------- launch ----------------
extern "C" void kernel_launch(void* const* d_in, const int* in_sizes, int n_in,
                              void* d_out, int out_size, void* d_ws, size_t ws_size,
                              hipStream_t stream){
  (void)in_sizes; (void)n_in; (void)out_size; (void)ws_size;
  const float* x      = (const float*)d_in[0];
  const float* Wih_f  = (const float*)d_in[1];
  const float* Whh_f  = (const float*)d_in[2];
  const float* bih_f  = (const float*)d_in[3];
  const float* bhh_f  = (const float*)d_in[4];
  const float* Wih_b  = (const float*)d_in[5];
  const float* Whh_b  = (const float*)d_in[6];
  const float* bih_b  = (const float*)d_in[7];
  const float* bhh_b  = (const float*)d_in[8];
  const float* g_in   = (const float*)d_in[9];
  const float* be_in  = (const float*)d_in[10];
  const float* g_fw   = (const float*)d_in[11];
  const float* be_fw  = (const float*)d_in[12];
  const float* g_bk   = (const float*)d_in[13];
  const float* be_bk  = (const float*)d_in[14];
  const float* g_sq   = (const float*)d_in[15];
  const float* be_sq  = (const float*)d_in[16];
  const float* Wsq    = (const float*)d_in[17];
  const float* bsq    = (const float*)d_in[18];
  const float* Wtop   = (const float*)d_in[19];
  const float* btop   = (const float*)d_in[20];
  const float* gkern  = (const float*)d_in[21];

  float* ws   = (float*)d_ws;
  float* xnT  = ws + OFF_XNT;
  float* WT   = ws + OFF_WT;
  float* hT   = ws + OFF_HT;
  float* part = ws + OFF_PART;
  float* hs   = ws + OFF_HS;
  float* xq   = ws + OFF_XQ;
  float* cmat = ws + OFF_CMAT;
  float* cosb = ws + OFF_COS;
  float* covg = ws + OFF_COV;
  float* Pg   = ws + OFF_PG;
  double* dar = (double*)(ws + OFF_PART);   // reused after LSTM finishes
  float* out  = (float*)d_out;

  k_zero<<<dim3(512), dim3(256), 0, stream>>>(hT, 131072);
  k_ln_in<<<dim3(SS*BB), dim3(256), 0, stream>>>(x, g_in, be_in, xnT);
  k_transW<<<dim3(128,56,2), dim3(256), 0, stream>>>(Wih_f, Whh_f, Wih_b, Whh_b, WT);
  for (int t = 0; t < SS; t++){
    k_step<<<dim3(256), dim3(256), 0, stream>>>(xnT, WT, hT, part, t);
    k_upd<<<dim3(256), dim3(256), 0, stream>>>(part, bih_f, bhh_f, bih_b, bhh_b,
                                               hT, ws + OFF_CT, hs, t);
  }
  k_lnproj<<<dim3(SS,2), dim3(256), 0, stream>>>(hs, g_fw, be_fw, g_bk, be_bk, Wsq, bsq, xq);
  k_topic<<<dim3(SS), dim3(256), 0, stream>>>(xq, g_sq, be_sq, Wtop, btop, out);
  k_pca1<<<dim3(64), dim3(256), 0, stream>>>(xq, cmat, covg);
  k_eig<<<dim3(64), dim3(64), 0, stream>>>(covg, dar, Pg);
  k_pca2<<<dim3(64), dim3(256), 0, stream>>>(cmat, Pg, gkern, cosb);
  k_pos<<<dim3(1), dim3(256), 0, stream>>>(cosb, out);
}